// Round 13
// baseline (698.869 us; speedup 1.0000x reference)
//
#include <hip/hip_runtime.h>
#include <math.h>

#define BB 16
#define NN 8192
#define CC 128
#define KK 128
#define LL 4

#define APX 40    // padded LDS stride for final_kernel staging
#define BPX 136   // LDS row stride for 128-wide transpose tiles

typedef short bf16x8 __attribute__((ext_vector_type(8)));
typedef float f32x4 __attribute__((ext_vector_type(4)));

typedef unsigned short u16;
typedef unsigned int u32;
typedef unsigned long long u64;

// cheap gelu: v * sigmoid(1.702 v)
__device__ __forceinline__ float gelu_f(float v){
  const float t = __builtin_amdgcn_exp2f(-2.45546696f * v);
  return v * __builtin_amdgcn_rcpf(1.0f + t);
}

__device__ __forceinline__ u16 f2bf(float f){
  u32 u = __float_as_uint(f);
  return (u16)((u + 0x7FFFu + ((u >> 16) & 1u)) >> 16);   // RNE
}
__device__ __forceinline__ float bf2f(u16 u){ return __uint_as_float(((u32)u) << 16); }
__device__ __forceinline__ u32 pk2(float a, float b){
  return (u32)f2bf(a) | ((u32)f2bf(b) << 16);
}

// async global->LDS, 16B per lane; LDS dst is wave-uniform base + lane*16
__device__ __forceinline__ void gll16(const u16* g, u16* l){
  __builtin_amdgcn_global_load_lds(
      (const __attribute__((address_space(1))) void*)g,
      (__attribute__((address_space(3))) void*)l, 16, 0, 0);
}

// ---------------------------------------------------------------- bases
__global__ __launch_bounds__(256) void bases_kernel(
    const float* __restrict__ X, const float* __restrict__ modes,
    u16* __restrict__ bcs, u16* __restrict__ bss,
    u16* __restrict__ bcT, u16* __restrict__ bsT,
    float* __restrict__ mA, float* __restrict__ sm2)
{
  __shared__ float smodes[2*KK];
  __shared__ u16 shc[64*BPX];
  __shared__ u16 shs[64*BPX];
  __shared__ float ssv[64];
  const int b = blockIdx.x;
  const int x0 = blockIdx.y*64;
  const int t = threadIdx.x;
  smodes[t] = modes[t];
  const int xl = t & 63;
  const int kq = t >> 6;
  const int x = x0 + xl;
  const float* xp = X + ((size_t)b*NN + x)*7;
  const float g0 = xp[3], g1 = xp[4], wv = xp[5], mv = xp[6];
  const float sv = wv * (float)NN;
  if (kq == 0){
    mA[b*NN + x] = mv;
    sm2[b*NN + x] = mv * sv;
    ssv[xl] = sv;
  }
  __syncthreads();
  #pragma unroll 4
  for (int kk = 0; kk < 32; ++kk){
    const int k = kq*32 + kk;
    const float tt = g0*smodes[2*k] + g1*smodes[2*k+1];
    float sn, cs;
    __sincosf(tt, &sn, &cs);
    shc[xl*BPX + k] = f2bf(cs*mv);
    shs[xl*BPX + k] = f2bf(sn*mv);
  }
  __syncthreads();
  for (int idx = t; idx < 64*16; idx += 256){
    const int row = idx >> 4, c16 = (idx & 15)*8;
    const size_t dst = ((size_t)b*NN + x0 + row)*KK + c16;
    *(uint4*)&bcT[dst] = *(const uint4*)&shc[row*BPX + c16];
    *(uint4*)&bsT[dst] = *(const uint4*)&shs[row*BPX + c16];
  }
  for (int idx = t; idx < 128*8; idx += 256){
    const int k = idx >> 3, x8 = (idx & 7)*8;
    uint4 vc, vs;
    u32* pc = (u32*)&vc;
    u32* ps = (u32*)&vs;
    #pragma unroll
    for (int e = 0; e < 4; ++e){
      const int xa = x8 + 2*e, xb2 = x8 + 2*e + 1;
      const float sa = ssv[xa], sb = ssv[xb2];
      pc[e] = pk2(bf2f(shc[xa*BPX+k])*sa, bf2f(shc[xb2*BPX+k])*sb);
      ps[e] = pk2(bf2f(shs[xa*BPX+k])*sa, bf2f(shs[xb2*BPX+k])*sb);
    }
    const size_t dst = ((size_t)b*KK + k)*NN + x0 + x8;
    *(uint4*)&bcs[dst] = vc;
    *(uint4*)&bss[dst] = vs;
  }
}

// ---------------------------------------------------------------- cvt (grid-parallel)
__global__ __launch_bounds__(256) void cvt_kernel(
    const float* __restrict__ convw, const float* __restrict__ fc1w,
    u16* __restrict__ cwb, u16* __restrict__ w1T)
{
  const int blk = blockIdx.x;
  const int t = threadIdx.x;
  if (blk < 64){
    const int base = blk*1024 + t*4;
    const float4 v = *(const float4*)&convw[base];
    ushort4 o;
    o.x = f2bf(v.x); o.y = f2bf(v.y); o.z = f2bf(v.z); o.w = f2bf(v.w);
    *(ushort4*)&cwb[base] = o;
  } else {
    const int i = (blk - 64)*1024 + t*4;
    const int f = i >> 7, c = i & 127;
    ushort4 o;
    o.x = f2bf(fc1w[(size_t)(c+0)*CC + f]);
    o.y = f2bf(fc1w[(size_t)(c+1)*CC + f]);
    o.z = f2bf(fc1w[(size_t)(c+2)*CC + f]);
    o.w = f2bf(fc1w[(size_t)(c+3)*CC + f]);
    *(ushort4*)&w1T[i] = o;
  }
}

// ---------------------------------------------------------------- fc0 -> hT, hI, x0[slot 0]
__global__ __launch_bounds__(256) void fc0_kernel(
    const float* __restrict__ X, const float* __restrict__ w, const float* __restrict__ bias,
    const float* __restrict__ sm2,
    u16* __restrict__ hT, u16* __restrict__ hI, float* __restrict__ x0out)
{
  __shared__ float sxin[3*128];
  __shared__ float sw[3*128];
  __shared__ float sb[128];
  __shared__ float ssm2[128];
  __shared__ u16 sht[128*BPX];   // [o][x]
  const int b = blockIdx.x;
  const int x0 = blockIdx.y*128;
  const int t = threadIdx.x;
  if (t < 128){
    sb[t] = bias[t];
    ssm2[t] = sm2[(size_t)b*NN + x0 + t];
    #pragma unroll
    for (int j = 0; j < 3; ++j){
      sw[j*128 + t] = w[j*128 + t];
      sxin[j*128 + t] = X[((size_t)b*NN + x0 + t)*7 + j];
    }
  }
  __syncthreads();
  const int o = t >> 1;
  const int xh = (t & 1)*64;
  const float w0v = sw[o], w1v = sw[128+o], w2v = sw[256+o], bv = sb[o];
  float xacc = 0.f;
  for (int x = xh; x < xh + 64; ++x){
    const float v = bv + sxin[x]*w0v + sxin[128+x]*w1v + sxin[256+x]*w2v;
    sht[o*BPX + x] = f2bf(v);
    xacc += v * ssm2[x];
  }
  xacc += __shfl_xor(xacc, 1);
  if ((t & 1) == 0) atomicAdd(&x0out[b*CC + o], xacc);
  __syncthreads();
  for (int idx = t; idx < 128*16; idx += 256){
    const int o2 = idx >> 4, x8 = (idx & 15)*8;
    *(uint4*)&hI[((size_t)b*CC + o2)*NN + x0 + x8] = *(const uint4*)&sht[o2*BPX + x8];
  }
  {
    const int x = t >> 1, oh = (t & 1)*64;
    #pragma unroll 2
    for (int j = 0; j < 8; ++j){
      const int ob = oh + j*8;
      uint4 qv;
      qv.x = (u32)sht[(ob+0)*BPX + x] | ((u32)sht[(ob+1)*BPX + x] << 16);
      qv.y = (u32)sht[(ob+2)*BPX + x] | ((u32)sht[(ob+3)*BPX + x] << 16);
      qv.z = (u32)sht[(ob+4)*BPX + x] | ((u32)sht[(ob+5)*BPX + x] << 16);
      qv.w = (u32)sht[(ob+6)*BPX + x] | ((u32)sht[(ob+7)*BPX + x] << 16);
      *(uint4*)&hT[((size_t)b*NN + x0 + x)*CC + ob] = qv;
    }
  }
}

// ---------------------------------------------------------------- proj v3: 512-thread, kind-split
__global__ __launch_bounds__(512) void proj512_kernel(
    const u16* __restrict__ hI, const u16* __restrict__ bcs, const u16* __restrict__ bss,
    u16* __restrict__ xcP, u16* __restrict__ xsP)
{
  __shared__ u16 sa[2][128*32];
  __shared__ u16 sb[2][128*32];
  const int b = blockIdx.x;
  const int z = blockIdx.y;            // 0..15, x-range of 512
  const int kind = blockIdx.z;         // 0 cos, 1 sin
  const int t = threadIdx.x;
  const int w = t >> 6, l = t & 63, lm = l & 15, q = l >> 4;
  const int ar = t >> 2, ac8 = (t & 3)*8;   // staging row 0..127, col*8
  const u16* Asrc = hI + (size_t)b*CC*NN + z*512;
  const u16* Bsrc = (kind ? bss : bcs) + (size_t)b*KK*NN + z*512;
  const f32x4 z4 = {0.f,0.f,0.f,0.f};
  f32x4 acc[8];
  #pragma unroll
  for (int nt = 0; nt < 8; ++nt) acc[nt] = z4;

  gll16(Asrc + (size_t)ar*NN + ac8, sa[0] + w*512);
  gll16(Bsrc + (size_t)ar*NN + ac8, sb[0] + w*512);
  for (int cs = 0; cs < 16; ++cs){
    __syncthreads();                       // buf[cs&1] DMA drained
    const int cur = cs & 1;
    if (cs < 15){                          // prefetch next chunk overlaps MFMA
      const int nb = cur ^ 1;
      const int c2 = (cs + 1)*32;
      gll16(Asrc + (size_t)ar*NN + c2 + ac8, sa[nb] + w*512);
      gll16(Bsrc + (size_t)ar*NN + c2 + ac8, sb[nb] + w*512);
    }
    const bf16x8 af = *(const bf16x8*)&sa[cur][(w*16 + lm)*32 + q*8];
    #pragma unroll
    for (int nt = 0; nt < 8; ++nt){
      const bf16x8 bf = *(const bf16x8*)&sb[cur][(nt*16 + lm)*32 + q*8];
      acc[nt] = __builtin_amdgcn_mfma_f32_16x16x32_bf16(af, bf, acc[nt], 0, 0, 0);
    }
  }
  u16* outp = kind ? xsP : xcP;
  const size_t pbase = ((size_t)z*BB + b)*CC*KK;
  #pragma unroll
  for (int nt = 0; nt < 8; ++nt){
    const int k = nt*16 + lm;
    #pragma unroll
    for (int r = 0; r < 4; ++r){
      const int i = w*16 + q*4 + r;
      __builtin_nontemporal_store(f2bf(acc[nt][r]), &outp[pbase + (size_t)i*KK + k]);
    }
  }
}

// ---------------------------------------------------------------- proj fallback (atomic, 256t)
__global__ __launch_bounds__(256) void proj_atomic_kernel(
    const u16* __restrict__ hI, const u16* __restrict__ bcs, const u16* __restrict__ bss,
    float* __restrict__ xc, float* __restrict__ xs)
{
  __shared__ u16 sa [2][128*32];
  __shared__ u16 sbc[2][128*32];
  __shared__ u16 sbs[2][128*32];
  const int b = blockIdx.x;
  const int z = blockIdx.y;
  const int t = threadIdx.x;
  const int w = t >> 6, l = t & 63, lm = l & 15, q = l >> 4;
  const int rr = l >> 2, c8 = (l & 3)*8;
  const u16* Asrc = hI + (size_t)b*CC*NN + z*512;
  const u16* Bc   = bcs + (size_t)b*KK*NN + z*512;
  const u16* Bs   = bss + (size_t)b*KK*NN + z*512;
  const f32x4 z4 = {0.f,0.f,0.f,0.f};
  f32x4 accC[2][8], accS[2][8];
  #pragma unroll
  for (int mt = 0; mt < 2; ++mt)
    #pragma unroll
    for (int nt = 0; nt < 8; ++nt){ accC[mt][nt] = z4; accS[mt][nt] = z4; }
  #pragma unroll
  for (int j = 0; j < 2; ++j){
    const int r = w*32 + j*16 + rr;
    gll16(Asrc + (size_t)r*NN + c8, sa [0] + (w*32 + j*16)*32);
    gll16(Bc   + (size_t)r*NN + c8, sbc[0] + (w*32 + j*16)*32);
    gll16(Bs   + (size_t)r*NN + c8, sbs[0] + (w*32 + j*16)*32);
  }
  for (int cs = 0; cs < 16; ++cs){
    __syncthreads();
    const int cur = cs & 1;
    if (cs < 15){
      const int nb = cur ^ 1;
      const int c2 = (cs + 1)*32;
      #pragma unroll
      for (int j = 0; j < 2; ++j){
        const int r = w*32 + j*16 + rr;
        gll16(Asrc + (size_t)r*NN + c2 + c8, sa [nb] + (w*32 + j*16)*32);
        gll16(Bc   + (size_t)r*NN + c2 + c8, sbc[nb] + (w*32 + j*16)*32);
        gll16(Bs   + (size_t)r*NN + c2 + c8, sbs[nb] + (w*32 + j*16)*32);
      }
    }
    const bf16x8 af0 = *(const bf16x8*)&sa[cur][(w*32      + lm)*32 + q*8];
    const bf16x8 af1 = *(const bf16x8*)&sa[cur][(w*32 + 16 + lm)*32 + q*8];
    #pragma unroll
    for (int nt = 0; nt < 8; ++nt){
      const bf16x8 bfc = *(const bf16x8*)&sbc[cur][(nt*16 + lm)*32 + q*8];
      const bf16x8 bfs = *(const bf16x8*)&sbs[cur][(nt*16 + lm)*32 + q*8];
      accC[0][nt] = __builtin_amdgcn_mfma_f32_16x16x32_bf16(af0, bfc, accC[0][nt], 0, 0, 0);
      accC[1][nt] = __builtin_amdgcn_mfma_f32_16x16x32_bf16(af1, bfc, accC[1][nt], 0, 0, 0);
      accS[0][nt] = __builtin_amdgcn_mfma_f32_16x16x32_bf16(af0, bfs, accS[0][nt], 0, 0, 0);
      accS[1][nt] = __builtin_amdgcn_mfma_f32_16x16x32_bf16(af1, bfs, accS[1][nt], 0, 0, 0);
    }
  }
  #pragma unroll
  for (int mt = 0; mt < 2; ++mt){
    #pragma unroll
    for (int nt = 0; nt < 8; ++nt){
      const int k = nt*16 + lm;
      #pragma unroll
      for (int r = 0; r < 4; ++r){
        const int i = w*32 + mt*16 + q*4 + r;
        atomicAdd(&xc[((size_t)b*CC + i)*KK + k],  accC[mt][nt][r]);
        atomicAdd(&xs[((size_t)b*CC + i)*KK + k], -accS[mt][nt][r]);
      }
    }
  }
}

// ---------------------------------------------------------------- reduce bf16 partials + f0
// blocks 0..511: 4 bi-rows each; u64 NT loads (4 bf16 per load, 32 independent in flight).
__global__ __launch_bounds__(128) void reduce_f0_kernel(
    const u16* __restrict__ xcP, const u16* __restrict__ xsP,
    float* __restrict__ xc, float* __restrict__ xs,
    const float* __restrict__ x0a, const float* __restrict__ w0l,
    float* __restrict__ f0b)
{
  const int blk = blockIdx.x;
  if (blk < 512){
    const int t = threadIdx.x;
    const int bi = blk*4 + (t >> 5);     // 0..2047
    const int kq = (t & 31)*4;           // k-quad base
    const size_t off = (size_t)bi*KK + kq;
    const size_t zstr = (size_t)BB*CC*KK;
    float c[4] = {0.f,0.f,0.f,0.f}, s[4] = {0.f,0.f,0.f,0.f};
    #pragma unroll
    for (int z = 0; z < 16; ++z){
      const u64 vc = __builtin_nontemporal_load((const u64*)&xcP[(size_t)z*zstr + off]);
      const u64 vs = __builtin_nontemporal_load((const u64*)&xsP[(size_t)z*zstr + off]);
      c[0] += bf2f((u16)(vc & 0xffff));         c[1] += bf2f((u16)((vc >> 16) & 0xffff));
      c[2] += bf2f((u16)((vc >> 32) & 0xffff)); c[3] += bf2f((u16)(vc >> 48));
      s[0] += bf2f((u16)(vs & 0xffff));         s[1] += bf2f((u16)((vs >> 16) & 0xffff));
      s[2] += bf2f((u16)((vs >> 32) & 0xffff)); s[3] += bf2f((u16)(vs >> 48));
    }
    float4 co = {c[0], c[1], c[2], c[3]};
    float4 so = {-s[0], -s[1], -s[2], -s[3]};
    *(float4*)&xc[off] = co;
    *(float4*)&xs[off] = so;
  } else {
    const int b = blk - 512, o = threadIdx.x;
    float acc = 0.f;
    for (int i = 0; i < CC; ++i) acc += x0a[b*CC+i] * w0l[(size_t)i*CC + o];
    f0b[b*CC+o] = acc * (1.0f/(float)NN);
  }
}

__global__ __launch_bounds__(128) void f0_kernel(
    const float* __restrict__ x0a, const float* __restrict__ w0l, float* __restrict__ f0b)
{
  const int b = blockIdx.x, o = threadIdx.x;
  float acc = 0.f;
  for (int i = 0; i < CC; ++i) acc += x0a[b*CC+i] * w0l[(size_t)i*CC + o];
  f0b[b*CC+o] = acc * (1.0f/(float)NN);
}

// ---------------------------------------------------------------- mix v3: unroll-8 grouped NT loads
__global__ __launch_bounds__(256) void mix_kernel(
    const float* __restrict__ xc, const float* __restrict__ xs,
    const float* __restrict__ wcl, const float* __restrict__ wsl,
    u16* __restrict__ fcb, u16* __restrict__ fsb)
{
  const int o  = blockIdx.x;           // 0..127
  const int kh = blockIdx.y;           // 0..1
  const int t = threadIdx.x;
  const int k = kh*64 + (t & 63);
  const int bq = t >> 6;               // 0..3 -> b = bq*4 + jb
  float aC[4] = {0.f,0.f,0.f,0.f}, aS[4] = {0.f,0.f,0.f,0.f};
  const float* wcp = wcl + (size_t)o*KK + k;
  const float* wsp = wsl + (size_t)o*KK + k;
  const float* xcp = xc + ((size_t)(bq*4)*CC)*KK + k;
  const float* xsp = xs + ((size_t)(bq*4)*CC)*KK + k;
  for (int i0 = 0; i0 < CC; i0 += 8){
    float wcv[8], wsv[8];
    #pragma unroll
    for (int u = 0; u < 8; ++u){
      wcv[u] = __builtin_nontemporal_load(&wcp[(size_t)(i0+u)*CC*KK]);
      wsv[u] = __builtin_nontemporal_load(&wsp[(size_t)(i0+u)*CC*KK]);
    }
    #pragma unroll
    for (int u = 0; u < 8; ++u){
      const int i = i0 + u;
      #pragma unroll
      for (int jb = 0; jb < 4; ++jb){
        const float xcv = xcp[((size_t)jb*CC + i)*KK];
        const float xsv = xsp[((size_t)jb*CC + i)*KK];
        aC[jb] += xcv*wcv[u] - xsv*wsv[u];
        aS[jb] += xsv*wcv[u] + xcv*wsv[u];
      }
    }
  }
  const float sc = 2.0f/(float)NN;
  #pragma unroll
  for (int jb = 0; jb < 4; ++jb){
    const int b = bq*4 + jb;
    fcb[((size_t)b*CC + o)*KK + k] = f2bf( aC[jb]*sc);
    fsb[((size_t)b*CC + o)*KK + k] = f2bf(-aS[jb]*sc);
  }
}

// ---------------------------------------------------------------- fused spectral+conv+gelu
__global__ __launch_bounds__(512) void fused_kernel(
    const u16* __restrict__ bcT, const u16* __restrict__ bsT, u16* __restrict__ hT,
    const u16* __restrict__ fcb, const u16* __restrict__ fsb,
    const u16* __restrict__ cwb, const float* __restrict__ cb,
    const float* __restrict__ f0b, const float* __restrict__ mA, const float* __restrict__ sm2,
    u16* __restrict__ hI, float* __restrict__ x0next, const int act)
{
  __shared__ u16 smem[24576];            // [0,16384): A dbuf ; [16384,24576): B dbuf
  __shared__ float sm[256], ssm2[256], sf0[128], scb[128];
  const int b  = blockIdx.x;
  const int x0 = blockIdx.y*256;
  const int t = threadIdx.x;
  const int w = t >> 6, l = t & 63, lm = l & 15, q = l >> 4;
  const int lr = l >> 2, lc8 = (l & 3)*8;
  if (t < 256){
    sm[t]   = mA[(size_t)b*NN + x0 + t];
    ssm2[t] = sm2[(size_t)b*NN + x0 + t];
  }
  if (t < 128){
    sf0[t]  = f0b[b*CC + t];
    scb[t]  = cb[t];
  }
  const u16* Asrc0 = bcT + ((size_t)b*NN + x0)*KK;
  const u16* Asrc1 = bsT + ((size_t)b*NN + x0)*KK;
  const u16* Asrc2 = hT  + ((size_t)b*NN + x0)*CC;
  const u16* Bsrc0 = fcb + (size_t)b*CC*KK;
  const u16* Bsrc1 = fsb + (size_t)b*CC*KK;
  const f32x4 z4 = {0.f,0.f,0.f,0.f};
  f32x4 acc[2][8];
  #pragma unroll
  for (int mt = 0; mt < 2; ++mt)
    #pragma unroll
    for (int nt = 0; nt < 8; ++nt) acc[mt][nt] = z4;

  {
    const int ar = w*16 + lr;
    gll16(Asrc0 + (size_t)ar*128 + lc8,         smem + w*512);
    gll16(Asrc0 + (size_t)(ar+128)*128 + lc8,   smem + 4096 + w*512);
    gll16(Bsrc0 + (size_t)ar*128 + lc8,         smem + 16384 + w*512);
  }
  for (int s = 0; s < 12; ++s){
    __syncthreads();
    const int curA = (s & 1)*8192;
    const int curB = 16384 + (s & 1)*4096;
    if (s < 11){
      const int s1 = s + 1;
      const int g = s1 >> 2, kk = (s1 & 3)*32;
      const u16* Ap = (g == 0) ? Asrc0 : (g == 1) ? Asrc1 : Asrc2;
      const u16* Bp = (g == 0) ? Bsrc0 : (g == 1) ? Bsrc1 : cwb;
      const int nbA = (s1 & 1)*8192;
      const int nbB = 16384 + (s1 & 1)*4096;
      const int ar = w*16 + lr;
      gll16(Ap + (size_t)ar*128 + kk + lc8,       smem + nbA + w*512);
      gll16(Ap + (size_t)(ar+128)*128 + kk + lc8, smem + nbA + 4096 + w*512);
      gll16(Bp + (size_t)ar*128 + kk + lc8,       smem + nbB + w*512);
    }
    const bf16x8 af0 = *(const bf16x8*)&smem[curA + (w*32      + lm)*32 + q*8];
    const bf16x8 af1 = *(const bf16x8*)&smem[curA + (w*32 + 16 + lm)*32 + q*8];
    #pragma unroll
    for (int nt = 0; nt < 8; ++nt){
      const bf16x8 bf = *(const bf16x8*)&smem[curB + (nt*16 + lm)*32 + q*8];
      acc[0][nt] = __builtin_amdgcn_mfma_f32_16x16x32_bf16(af0, bf, acc[0][nt], 0, 0, 0);
      acc[1][nt] = __builtin_amdgcn_mfma_f32_16x16x32_bf16(af1, bf, acc[1][nt], 0, 0, 0);
    }
  }
  // epilogue in two 128-x passes; smem reused as [x][o] stride BPX
  #pragma unroll
  for (int pass = 0; pass < 2; ++pass){
    __syncthreads();
    if ((w >> 2) == pass){
      float xpart[8];
      #pragma unroll
      for (int nt = 0; nt < 8; ++nt) xpart[nt] = 0.f;
      const int wl = w & 3;
      #pragma unroll
      for (int mt = 0; mt < 2; ++mt){
        const int xg = w*32 + mt*16 + q*4;
        const int xl = wl*32 + mt*16 + q*4;
        #pragma unroll
        for (int nt = 0; nt < 8; ++nt){
          const int o = nt*16 + lm;
          const float f0v = sf0[o], cbv = scb[o];
          float v0 = acc[mt][nt][0] + f0v*sm[xg+0] + cbv;
          float v1 = acc[mt][nt][1] + f0v*sm[xg+1] + cbv;
          float v2 = acc[mt][nt][2] + f0v*sm[xg+2] + cbv;
          float v3 = acc[mt][nt][3] + f0v*sm[xg+3] + cbv;
          if (act){ v0 = gelu_f(v0); v1 = gelu_f(v1); v2 = gelu_f(v2); v3 = gelu_f(v3); }
          smem[(xl+0)*BPX + o] = f2bf(v0);
          smem[(xl+1)*BPX + o] = f2bf(v1);
          smem[(xl+2)*BPX + o] = f2bf(v2);
          smem[(xl+3)*BPX + o] = f2bf(v3);
          if (act){
            uint2 st;
            st.x = pk2(v0, v1);
            st.y = pk2(v2, v3);
            *(uint2*)&hI[((size_t)b*CC + o)*NN + x0 + xg] = st;
            xpart[nt] += v0*ssm2[xg+0] + v1*ssm2[xg+1] + v2*ssm2[xg+2] + v3*ssm2[xg+3];
          }
        }
      }
      if (act){
        #pragma unroll
        for (int nt = 0; nt < 8; ++nt){
          float v = xpart[nt];
          v += __shfl_xor(v, 16);
          v += __shfl_xor(v, 32);
          if (q == 0) atomicAdd(&x0next[b*CC + nt*16 + lm], v);
        }
      }
    }
    __syncthreads();
    {
      const int xr = t >> 2;
      const int oq = (t & 3)*32;
      const size_t dst = ((size_t)b*NN + x0 + pass*128 + xr)*CC + oq;
      #pragma unroll
      for (int j = 0; j < 4; ++j){
        const uint4 v = *(const uint4*)&smem[xr*BPX + oq + j*8];
        *(uint4*)&hT[dst + j*8] = v;
      }
    }
  }
}

// ---------------------------------------------------------------- final MLP (MFMA)
__global__ __launch_bounds__(256) void final_kernel(
    const u16* __restrict__ hT, const u16* __restrict__ w1T,
    const float* __restrict__ b1, const float* __restrict__ w2, const float* __restrict__ b2,
    float* __restrict__ out)
{
  __shared__ u16 sa[128*APX];
  __shared__ u16 sbt[128*APX];
  __shared__ float sb1[128], sw2[128];
  const int b  = blockIdx.x;
  const int x0 = blockIdx.y*128;
  const int t = threadIdx.x;
  const int w = t >> 6, l = t & 63, lm = l & 15, q = l >> 4;
  if (t < 128){ sb1[t] = b1[t]; sw2[t] = w2[t]; }
  const float b2v = b2[0];
  const f32x4 z4 = {0.f,0.f,0.f,0.f};
  f32x4 acc[2][8];
  #pragma unroll
  for (int mt = 0; mt < 2; ++mt)
    #pragma unroll
    for (int nt = 0; nt < 8; ++nt) acc[mt][nt] = z4;
  const u16* Ap = hT + ((size_t)b*NN + x0)*CC;
  const int row = t >> 2, ch = (t & 3)*8;
  for (int s = 0; s < 4; ++s){
    const int kk = s*32;
    __syncthreads();
    #pragma unroll
    for (int h = 0; h < 2; ++h){
      const int r = row + h*64;
      *(uint4*)&sa [r*APX + ch] = *(const uint4*)&Ap [(size_t)r*CC + kk + ch];
      *(uint4*)&sbt[r*APX + ch] = *(const uint4*)&w1T[(size_t)r*CC + kk + ch];
    }
    __syncthreads();
    bf16x8 af[2];
    af[0] = *(const bf16x8*)&sa[(w*32      + lm)*APX + q*8];
    af[1] = *(const bf16x8*)&sa[(w*32 + 16 + lm)*APX + q*8];
    #pragma unroll
    for (int nt = 0; nt < 8; ++nt){
      const bf16x8 bf = *(const bf16x8*)&sbt[(nt*16 + lm)*APX + q*8];
      acc[0][nt] = __builtin_amdgcn_mfma_f32_16x16x32_bf16(af[0], bf, acc[0][nt], 0, 0, 0);
      acc[1][nt] = __builtin_amdgcn_mfma_f32_16x16x32_bf16(af[1], bf, acc[1][nt], 0, 0, 0);
    }
  }
  #pragma unroll
  for (int mt = 0; mt < 2; ++mt){
    #pragma unroll
    for (int r = 0; r < 4; ++r){
      float s = 0.f;
      #pragma unroll
      for (int nt = 0; nt < 8; ++nt){
        const int f = nt*16 + lm;
        s += gelu_f(acc[mt][nt][r] + sb1[f]) * sw2[f];
      }
      s += __shfl_xor(s, 1);
      s += __shfl_xor(s, 2);
      s += __shfl_xor(s, 4);
      s += __shfl_xor(s, 8);
      if (lm == 0){
        const int x = x0 + w*32 + mt*16 + q*4 + r;
        out[(size_t)b*NN + x] = s + b2v;
      }
    }
  }
}

// ---------------------------------------------------------------- host
extern "C" void kernel_launch(void* const* d_in, const int* in_sizes, int n_in,
                              void* d_out, int out_size, void* d_ws, size_t ws_size,
                              hipStream_t stream)
{
  const float* X     = (const float*)d_in[0];
  const float* modes = (const float*)d_in[1];
  const float* fc0w  = (const float*)d_in[2];
  const float* fc0b  = (const float*)d_in[3];
  const float* wc    = (const float*)d_in[4];
  const float* wsm   = (const float*)d_in[5];
  const float* w0    = (const float*)d_in[6];
  const float* convw = (const float*)d_in[7];
  const float* convb = (const float*)d_in[8];
  const float* fc1w  = (const float*)d_in[9];
  const float* fc1b  = (const float*)d_in[10];
  const float* fc2w  = (const float*)d_in[11];
  const float* fc2b  = (const float*)d_in[12];
  float* out = (float*)d_out;

  const size_t nBKN = (size_t)BB*KK*NN;
  const size_t nBCK = (size_t)BB*CC*KK;
  const size_t nBC  = (size_t)BB*CC;
  const size_t nBN  = (size_t)BB*NN;

  // Path A: bf16 partials (2 x 16 x nBCK x 2B)
  const size_t need_A = 6*nBKN*2 + 2*(size_t)16*nBCK*2 + 2*nBCK*4 + 4*nBC*4
                      + 2*nBCK*2 + nBC*4 + 2*nBN*4 + (size_t)LL*CC*CC*2 + (size_t)CC*CC*2;
  const bool pathA = (ws_size >= need_A);

  char* p = (char*)d_ws;
  u16* bcs = (u16*)p; p += nBKN*2;
  u16* bss = (u16*)p; p += nBKN*2;
  u16* bcT = (u16*)p; p += nBKN*2;
  u16* bsT = (u16*)p; p += nBKN*2;
  u16* hI  = (u16*)p; p += nBKN*2;
  u16* hT  = (u16*)p; p += nBKN*2;
  u16* xcP = nullptr; u16* xsP = nullptr;
  if (pathA){
    xcP = (u16*)p; p += (size_t)16*nBCK*2;
    xsP = (u16*)p; p += (size_t)16*nBCK*2;
  }
  float* xcA = (float*)p; p += nBCK*4;
  float* xsA = (float*)p; p += nBCK*4;
  float* x0A = (float*)p; p += 4*nBC*4;    // 4 per-layer slots
  u16* fcb = (u16*)p; p += nBCK*2;
  u16* fsb = (u16*)p; p += nBCK*2;
  float* f0b = (float*)p; p += nBC*4;
  float* mA  = (float*)p; p += nBN*4;
  float* sm2 = (float*)p; p += nBN*4;
  u16* cwb = (u16*)p; p += (size_t)LL*CC*CC*2;
  u16* w1T = (u16*)p; p += (size_t)CC*CC*2;

  hipMemsetAsync(x0A, 0, 4*nBC*sizeof(float), stream);
  cvt_kernel<<<dim3(80), 256, 0, stream>>>(convw, fc1w, cwb, w1T);
  bases_kernel<<<dim3(BB, NN/64), 256, 0, stream>>>(X, modes, bcs, bss, bcT, bsT, mA, sm2);
  fc0_kernel<<<dim3(BB, NN/128), 256, 0, stream>>>(X, fc0w, fc0b, sm2, hT, hI, x0A);

  for (int l = 0; l < LL; ++l){
    if (pathA){
      proj512_kernel<<<dim3(BB, 16, 2), 512, 0, stream>>>(hI, bcs, bss, xcP, xsP);
      reduce_f0_kernel<<<dim3(512 + BB), 128, 0, stream>>>(xcP, xsP, xcA, xsA,
          x0A + (size_t)l*nBC, w0 + (size_t)l*CC*CC, f0b);
    } else {
      hipMemsetAsync(xcA, 0, 2*nBCK*sizeof(float), stream);
      proj_atomic_kernel<<<dim3(BB, 16), 256, 0, stream>>>(hI, bcs, bss, xcA, xsA);
      f0_kernel<<<dim3(BB), 128, 0, stream>>>(x0A + (size_t)l*nBC, w0 + (size_t)l*CC*CC, f0b);
    }
    mix_kernel<<<dim3(128, 2), 256, 0, stream>>>(xcA, xsA,
        wc + (size_t)l*CC*CC*KK, wsm + (size_t)l*CC*CC*KK, fcb, fsb);
    fused_kernel<<<dim3(BB, NN/256), 512, 0, stream>>>(
        bcT, bsT, hT, fcb, fsb,
        cwb + (size_t)l*CC*CC, convb + (size_t)l*CC,
        f0b, mA, sm2, hI,
        x0A + (size_t)(l+1 < LL ? l+1 : 0)*nBC,
        (l < LL-1) ? 1 : 0);
  }
  final_kernel<<<dim3(BB, NN/128), 256, 0, stream>>>(hT, w1T, fc1b, fc2w, fc2b, out);
}

// Round 14
// 618.886 us; speedup vs baseline: 1.1292x; 1.1292x over previous
//
#include <hip/hip_runtime.h>
#include <math.h>

#define BB 16
#define NN 8192
#define CC 128
#define KK 128
#define LL 4

#define APX 40    // padded LDS stride for final_kernel staging
#define BPX 136   // LDS row stride for 128-wide transpose tiles

typedef short bf16x8 __attribute__((ext_vector_type(8)));
typedef float f32x4 __attribute__((ext_vector_type(4)));

typedef unsigned short u16;
typedef unsigned int u32;

// cheap gelu: v * sigmoid(1.702 v)
__device__ __forceinline__ float gelu_f(float v){
  const float t = __builtin_amdgcn_exp2f(-2.45546696f * v);
  return v * __builtin_amdgcn_rcpf(1.0f + t);
}

__device__ __forceinline__ u16 f2bf(float f){
  u32 u = __float_as_uint(f);
  return (u16)((u + 0x7FFFu + ((u >> 16) & 1u)) >> 16);   // RNE
}
__device__ __forceinline__ float bf2f(u16 u){ return __uint_as_float(((u32)u) << 16); }
__device__ __forceinline__ u32 pk2(float a, float b){
  return (u32)f2bf(a) | ((u32)f2bf(b) << 16);
}

// async global->LDS, 16B per lane; LDS dst is wave-uniform base + lane*16
__device__ __forceinline__ void gll16(const u16* g, u16* l){
  __builtin_amdgcn_global_load_lds(
      (const __attribute__((address_space(1))) void*)g,
      (__attribute__((address_space(3))) void*)l, 16, 0, 0);
}

// ---------------------------------------------------------------- bases
__global__ __launch_bounds__(256) void bases_kernel(
    const float* __restrict__ X, const float* __restrict__ modes,
    u16* __restrict__ bcs, u16* __restrict__ bss,
    u16* __restrict__ bcT, u16* __restrict__ bsT,
    float* __restrict__ mA, float* __restrict__ sm2)
{
  __shared__ float smodes[2*KK];
  __shared__ u16 shc[64*BPX];
  __shared__ u16 shs[64*BPX];
  __shared__ float ssv[64];
  const int b = blockIdx.x;
  const int x0 = blockIdx.y*64;
  const int t = threadIdx.x;
  smodes[t] = modes[t];
  const int xl = t & 63;
  const int kq = t >> 6;
  const int x = x0 + xl;
  const float* xp = X + ((size_t)b*NN + x)*7;
  const float g0 = xp[3], g1 = xp[4], wv = xp[5], mv = xp[6];
  const float sv = wv * (float)NN;
  if (kq == 0){
    mA[b*NN + x] = mv;
    sm2[b*NN + x] = mv * sv;
    ssv[xl] = sv;
  }
  __syncthreads();
  #pragma unroll 4
  for (int kk = 0; kk < 32; ++kk){
    const int k = kq*32 + kk;
    const float tt = g0*smodes[2*k] + g1*smodes[2*k+1];
    float sn, cs;
    __sincosf(tt, &sn, &cs);
    shc[xl*BPX + k] = f2bf(cs*mv);
    shs[xl*BPX + k] = f2bf(sn*mv);
  }
  __syncthreads();
  for (int idx = t; idx < 64*16; idx += 256){
    const int row = idx >> 4, c16 = (idx & 15)*8;
    const size_t dst = ((size_t)b*NN + x0 + row)*KK + c16;
    *(uint4*)&bcT[dst] = *(const uint4*)&shc[row*BPX + c16];
    *(uint4*)&bsT[dst] = *(const uint4*)&shs[row*BPX + c16];
  }
  for (int idx = t; idx < 128*8; idx += 256){
    const int k = idx >> 3, x8 = (idx & 7)*8;
    uint4 vc, vs;
    u32* pc = (u32*)&vc;
    u32* ps = (u32*)&vs;
    #pragma unroll
    for (int e = 0; e < 4; ++e){
      const int xa = x8 + 2*e, xb2 = x8 + 2*e + 1;
      const float sa = ssv[xa], sb = ssv[xb2];
      pc[e] = pk2(bf2f(shc[xa*BPX+k])*sa, bf2f(shc[xb2*BPX+k])*sb);
      ps[e] = pk2(bf2f(shs[xa*BPX+k])*sa, bf2f(shs[xb2*BPX+k])*sb);
    }
    const size_t dst = ((size_t)b*KK + k)*NN + x0 + x8;
    *(uint4*)&bcs[dst] = vc;
    *(uint4*)&bss[dst] = vs;
  }
}

// ---------------------------------------------------------------- cvt (grid-parallel)
__global__ __launch_bounds__(256) void cvt_kernel(
    const float* __restrict__ convw, const float* __restrict__ fc1w,
    u16* __restrict__ cwb, u16* __restrict__ w1T)
{
  const int blk = blockIdx.x;
  const int t = threadIdx.x;
  if (blk < 64){
    const int base = blk*1024 + t*4;
    const float4 v = *(const float4*)&convw[base];
    ushort4 o;
    o.x = f2bf(v.x); o.y = f2bf(v.y); o.z = f2bf(v.z); o.w = f2bf(v.w);
    *(ushort4*)&cwb[base] = o;
  } else {
    const int i = (blk - 64)*1024 + t*4;
    const int f = i >> 7, c = i & 127;
    ushort4 o;
    o.x = f2bf(fc1w[(size_t)(c+0)*CC + f]);
    o.y = f2bf(fc1w[(size_t)(c+1)*CC + f]);
    o.z = f2bf(fc1w[(size_t)(c+2)*CC + f]);
    o.w = f2bf(fc1w[(size_t)(c+3)*CC + f]);
    *(ushort4*)&w1T[i] = o;
  }
}

// ---------------------------------------------------------------- fc0 -> hT, hI, x0[slot 0]
__global__ __launch_bounds__(256) void fc0_kernel(
    const float* __restrict__ X, const float* __restrict__ w, const float* __restrict__ bias,
    const float* __restrict__ sm2,
    u16* __restrict__ hT, u16* __restrict__ hI, float* __restrict__ x0out)
{
  __shared__ float sxin[3*128];
  __shared__ float sw[3*128];
  __shared__ float sb[128];
  __shared__ float ssm2[128];
  __shared__ u16 sht[128*BPX];   // [o][x]
  const int b = blockIdx.x;
  const int x0 = blockIdx.y*128;
  const int t = threadIdx.x;
  if (t < 128){
    sb[t] = bias[t];
    ssm2[t] = sm2[(size_t)b*NN + x0 + t];
    #pragma unroll
    for (int j = 0; j < 3; ++j){
      sw[j*128 + t] = w[j*128 + t];
      sxin[j*128 + t] = X[((size_t)b*NN + x0 + t)*7 + j];
    }
  }
  __syncthreads();
  const int o = t >> 1;
  const int xh = (t & 1)*64;
  const float w0v = sw[o], w1v = sw[128+o], w2v = sw[256+o], bv = sb[o];
  float xacc = 0.f;
  for (int x = xh; x < xh + 64; ++x){
    const float v = bv + sxin[x]*w0v + sxin[128+x]*w1v + sxin[256+x]*w2v;
    sht[o*BPX + x] = f2bf(v);
    xacc += v * ssm2[x];
  }
  xacc += __shfl_xor(xacc, 1);
  if ((t & 1) == 0) atomicAdd(&x0out[b*CC + o], xacc);
  __syncthreads();
  for (int idx = t; idx < 128*16; idx += 256){
    const int o2 = idx >> 4, x8 = (idx & 15)*8;
    *(uint4*)&hI[((size_t)b*CC + o2)*NN + x0 + x8] = *(const uint4*)&sht[o2*BPX + x8];
  }
  {
    const int x = t >> 1, oh = (t & 1)*64;
    #pragma unroll 2
    for (int j = 0; j < 8; ++j){
      const int ob = oh + j*8;
      uint4 qv;
      qv.x = (u32)sht[(ob+0)*BPX + x] | ((u32)sht[(ob+1)*BPX + x] << 16);
      qv.y = (u32)sht[(ob+2)*BPX + x] | ((u32)sht[(ob+3)*BPX + x] << 16);
      qv.z = (u32)sht[(ob+4)*BPX + x] | ((u32)sht[(ob+5)*BPX + x] << 16);
      qv.w = (u32)sht[(ob+6)*BPX + x] | ((u32)sht[(ob+7)*BPX + x] << 16);
      *(uint4*)&hT[((size_t)b*NN + x0 + x)*CC + ob] = qv;
    }
  }
}

// ---------------------------------------------------------------- proj v3: 512-thread, kind-split
__global__ __launch_bounds__(512) void proj512_kernel(
    const u16* __restrict__ hI, const u16* __restrict__ bcs, const u16* __restrict__ bss,
    u16* __restrict__ xcP, u16* __restrict__ xsP)
{
  __shared__ u16 sa[2][128*32];
  __shared__ u16 sb[2][128*32];
  const int b = blockIdx.x;
  const int z = blockIdx.y;            // 0..15, x-range of 512
  const int kind = blockIdx.z;         // 0 cos, 1 sin
  const int t = threadIdx.x;
  const int w = t >> 6, l = t & 63, lm = l & 15, q = l >> 4;
  const int ar = t >> 2, ac8 = (t & 3)*8;   // staging row 0..127, col*8
  const u16* Asrc = hI + (size_t)b*CC*NN + z*512;
  const u16* Bsrc = (kind ? bss : bcs) + (size_t)b*KK*NN + z*512;
  const f32x4 z4 = {0.f,0.f,0.f,0.f};
  f32x4 acc[8];
  #pragma unroll
  for (int nt = 0; nt < 8; ++nt) acc[nt] = z4;

  gll16(Asrc + (size_t)ar*NN + ac8, sa[0] + w*512);
  gll16(Bsrc + (size_t)ar*NN + ac8, sb[0] + w*512);
  for (int cs = 0; cs < 16; ++cs){
    __syncthreads();                       // buf[cs&1] DMA drained
    const int cur = cs & 1;
    if (cs < 15){                          // prefetch next chunk overlaps MFMA
      const int nb = cur ^ 1;
      const int c2 = (cs + 1)*32;
      gll16(Asrc + (size_t)ar*NN + c2 + ac8, sa[nb] + w*512);
      gll16(Bsrc + (size_t)ar*NN + c2 + ac8, sb[nb] + w*512);
    }
    const bf16x8 af = *(const bf16x8*)&sa[cur][(w*16 + lm)*32 + q*8];
    #pragma unroll
    for (int nt = 0; nt < 8; ++nt){
      const bf16x8 bf = *(const bf16x8*)&sb[cur][(nt*16 + lm)*32 + q*8];
      acc[nt] = __builtin_amdgcn_mfma_f32_16x16x32_bf16(af, bf, acc[nt], 0, 0, 0);
    }
  }
  u16* outp = kind ? xsP : xcP;
  const size_t pbase = ((size_t)z*BB + b)*CC*KK;
  #pragma unroll
  for (int nt = 0; nt < 8; ++nt){
    const int k = nt*16 + lm;
    #pragma unroll
    for (int r = 0; r < 4; ++r){
      const int i = w*16 + q*4 + r;
      __builtin_nontemporal_store(f2bf(acc[nt][r]), &outp[pbase + (size_t)i*KK + k]);
    }
  }
}

// ---------------------------------------------------------------- proj fallback (atomic, 256t)
__global__ __launch_bounds__(256) void proj_atomic_kernel(
    const u16* __restrict__ hI, const u16* __restrict__ bcs, const u16* __restrict__ bss,
    float* __restrict__ xc, float* __restrict__ xs)
{
  __shared__ u16 sa [2][128*32];
  __shared__ u16 sbc[2][128*32];
  __shared__ u16 sbs[2][128*32];
  const int b = blockIdx.x;
  const int z = blockIdx.y;
  const int t = threadIdx.x;
  const int w = t >> 6, l = t & 63, lm = l & 15, q = l >> 4;
  const int rr = l >> 2, c8 = (l & 3)*8;
  const u16* Asrc = hI + (size_t)b*CC*NN + z*512;
  const u16* Bc   = bcs + (size_t)b*KK*NN + z*512;
  const u16* Bs   = bss + (size_t)b*KK*NN + z*512;
  const f32x4 z4 = {0.f,0.f,0.f,0.f};
  f32x4 accC[2][8], accS[2][8];
  #pragma unroll
  for (int mt = 0; mt < 2; ++mt)
    #pragma unroll
    for (int nt = 0; nt < 8; ++nt){ accC[mt][nt] = z4; accS[mt][nt] = z4; }
  #pragma unroll
  for (int j = 0; j < 2; ++j){
    const int r = w*32 + j*16 + rr;
    gll16(Asrc + (size_t)r*NN + c8, sa [0] + (w*32 + j*16)*32);
    gll16(Bc   + (size_t)r*NN + c8, sbc[0] + (w*32 + j*16)*32);
    gll16(Bs   + (size_t)r*NN + c8, sbs[0] + (w*32 + j*16)*32);
  }
  for (int cs = 0; cs < 16; ++cs){
    __syncthreads();
    const int cur = cs & 1;
    if (cs < 15){
      const int nb = cur ^ 1;
      const int c2 = (cs + 1)*32;
      #pragma unroll
      for (int j = 0; j < 2; ++j){
        const int r = w*32 + j*16 + rr;
        gll16(Asrc + (size_t)r*NN + c2 + c8, sa [nb] + (w*32 + j*16)*32);
        gll16(Bc   + (size_t)r*NN + c2 + c8, sbc[nb] + (w*32 + j*16)*32);
        gll16(Bs   + (size_t)r*NN + c2 + c8, sbs[nb] + (w*32 + j*16)*32);
      }
    }
    const bf16x8 af0 = *(const bf16x8*)&sa[cur][(w*32      + lm)*32 + q*8];
    const bf16x8 af1 = *(const bf16x8*)&sa[cur][(w*32 + 16 + lm)*32 + q*8];
    #pragma unroll
    for (int nt = 0; nt < 8; ++nt){
      const bf16x8 bfc = *(const bf16x8*)&sbc[cur][(nt*16 + lm)*32 + q*8];
      const bf16x8 bfs = *(const bf16x8*)&sbs[cur][(nt*16 + lm)*32 + q*8];
      accC[0][nt] = __builtin_amdgcn_mfma_f32_16x16x32_bf16(af0, bfc, accC[0][nt], 0, 0, 0);
      accC[1][nt] = __builtin_amdgcn_mfma_f32_16x16x32_bf16(af1, bfc, accC[1][nt], 0, 0, 0);
      accS[0][nt] = __builtin_amdgcn_mfma_f32_16x16x32_bf16(af0, bfs, accS[0][nt], 0, 0, 0);
      accS[1][nt] = __builtin_amdgcn_mfma_f32_16x16x32_bf16(af1, bfs, accS[1][nt], 0, 0, 0);
    }
  }
  #pragma unroll
  for (int mt = 0; mt < 2; ++mt){
    #pragma unroll
    for (int nt = 0; nt < 8; ++nt){
      const int k = nt*16 + lm;
      #pragma unroll
      for (int r = 0; r < 4; ++r){
        const int i = w*32 + mt*16 + q*4 + r;
        atomicAdd(&xc[((size_t)b*CC + i)*KK + k],  accC[mt][nt][r]);
        atomicAdd(&xs[((size_t)b*CC + i)*KK + k], -accS[mt][nt][r]);
      }
    }
  }
}

// ---------------------------------------------------------------- reduce bf16 partials + f0 (r11 form)
__global__ __launch_bounds__(128) void reduce_f0_kernel(
    const u16* __restrict__ xcP, const u16* __restrict__ xsP,
    float* __restrict__ xc, float* __restrict__ xs,
    const float* __restrict__ x0a, const float* __restrict__ w0l,
    float* __restrict__ f0b)
{
  const int blk = blockIdx.x;
  if (blk < 1024){
    const int t = threadIdx.x;
    const int bi = blk*2 + (t >> 6);     // 0..2047
    const int kp = (t & 63);             // k-pair 0..63
    const size_t off = (size_t)bi*KK + kp*2;
    const size_t zstr = (size_t)BB*CC*KK;
    float c0 = 0.f, c1 = 0.f, s0 = 0.f, s1 = 0.f;
    #pragma unroll
    for (int z = 0; z < 16; ++z){
      const u32 vc = __builtin_nontemporal_load((const u32*)&xcP[(size_t)z*zstr + off]);
      const u32 vs = __builtin_nontemporal_load((const u32*)&xsP[(size_t)z*zstr + off]);
      c0 += bf2f((u16)(vc & 0xffff));  c1 += bf2f((u16)(vc >> 16));
      s0 += bf2f((u16)(vs & 0xffff));  s1 += bf2f((u16)(vs >> 16));
    }
    xc[off]   = c0;   xc[off+1] = c1;
    xs[off]   = -s0;  xs[off+1] = -s1;
  } else {
    const int b = blk - 1024, o = threadIdx.x;
    float acc = 0.f;
    for (int i = 0; i < CC; ++i) acc += x0a[b*CC+i] * w0l[(size_t)i*CC + o];
    f0b[b*CC+o] = acc * (1.0f/(float)NN);
  }
}

__global__ __launch_bounds__(128) void f0_kernel(
    const float* __restrict__ x0a, const float* __restrict__ w0l, float* __restrict__ f0b)
{
  const int b = blockIdx.x, o = threadIdx.x;
  float acc = 0.f;
  for (int i = 0; i < CC; ++i) acc += x0a[b*CC+i] * w0l[(size_t)i*CC + o];
  f0b[b*CC+o] = acc * (1.0f/(float)NN);
}

// ---------------------------------------------------------------- mix v4: 512 blocks (2/CU), unroll-4
// grid (128 o, 4 kq); thread: k = kq*32 + (t&31), b-group = t>>5 (2 b each).
// Weight elements still read exactly once; i-accumulation order unchanged vs r11.
__global__ __launch_bounds__(256) void mix_kernel(
    const float* __restrict__ xc, const float* __restrict__ xs,
    const float* __restrict__ wcl, const float* __restrict__ wsl,
    u16* __restrict__ fcb, u16* __restrict__ fsb)
{
  const int o  = blockIdx.x;           // 0..127
  const int kq = blockIdx.y;           // 0..3
  const int t = threadIdx.x;
  const int k = kq*32 + (t & 31);
  const int bg = t >> 5;               // 0..7 -> b = bg*2 + jb
  float aC[2] = {0.f,0.f}, aS[2] = {0.f,0.f};
  const float* wcp = wcl + (size_t)o*KK + k;
  const float* wsp = wsl + (size_t)o*KK + k;
  const float* xcp = xc + ((size_t)(bg*2)*CC)*KK + k;
  const float* xsp = xs + ((size_t)(bg*2)*CC)*KK + k;
  for (int i0 = 0; i0 < CC; i0 += 4){
    float wcv[4], wsv[4];
    #pragma unroll
    for (int u = 0; u < 4; ++u){
      wcv[u] = __builtin_nontemporal_load(&wcp[(size_t)(i0+u)*CC*KK]);
      wsv[u] = __builtin_nontemporal_load(&wsp[(size_t)(i0+u)*CC*KK]);
    }
    #pragma unroll
    for (int u = 0; u < 4; ++u){
      const int i = i0 + u;
      #pragma unroll
      for (int jb = 0; jb < 2; ++jb){
        const float xcv = xcp[((size_t)jb*CC + i)*KK];
        const float xsv = xsp[((size_t)jb*CC + i)*KK];
        aC[jb] += xcv*wcv[u] - xsv*wsv[u];
        aS[jb] += xsv*wcv[u] + xcv*wsv[u];
      }
    }
  }
  const float sc = 2.0f/(float)NN;
  #pragma unroll
  for (int jb = 0; jb < 2; ++jb){
    const int b = bg*2 + jb;
    fcb[((size_t)b*CC + o)*KK + k] = f2bf( aC[jb]*sc);
    fsb[((size_t)b*CC + o)*KK + k] = f2bf(-aS[jb]*sc);
  }
}

// ---------------------------------------------------------------- fused spectral+conv+gelu
__global__ __launch_bounds__(512) void fused_kernel(
    const u16* __restrict__ bcT, const u16* __restrict__ bsT, u16* __restrict__ hT,
    const u16* __restrict__ fcb, const u16* __restrict__ fsb,
    const u16* __restrict__ cwb, const float* __restrict__ cb,
    const float* __restrict__ f0b, const float* __restrict__ mA, const float* __restrict__ sm2,
    u16* __restrict__ hI, float* __restrict__ x0next, const int act)
{
  __shared__ u16 smem[24576];            // [0,16384): A dbuf ; [16384,24576): B dbuf
  __shared__ float sm[256], ssm2[256], sf0[128], scb[128];
  const int b  = blockIdx.x;
  const int x0 = blockIdx.y*256;
  const int t = threadIdx.x;
  const int w = t >> 6, l = t & 63, lm = l & 15, q = l >> 4;
  const int lr = l >> 2, lc8 = (l & 3)*8;
  if (t < 256){
    sm[t]   = mA[(size_t)b*NN + x0 + t];
    ssm2[t] = sm2[(size_t)b*NN + x0 + t];
  }
  if (t < 128){
    sf0[t]  = f0b[b*CC + t];
    scb[t]  = cb[t];
  }
  const u16* Asrc0 = bcT + ((size_t)b*NN + x0)*KK;
  const u16* Asrc1 = bsT + ((size_t)b*NN + x0)*KK;
  const u16* Asrc2 = hT  + ((size_t)b*NN + x0)*CC;
  const u16* Bsrc0 = fcb + (size_t)b*CC*KK;
  const u16* Bsrc1 = fsb + (size_t)b*CC*KK;
  const f32x4 z4 = {0.f,0.f,0.f,0.f};
  f32x4 acc[2][8];
  #pragma unroll
  for (int mt = 0; mt < 2; ++mt)
    #pragma unroll
    for (int nt = 0; nt < 8; ++nt) acc[mt][nt] = z4;

  {
    const int ar = w*16 + lr;
    gll16(Asrc0 + (size_t)ar*128 + lc8,         smem + w*512);
    gll16(Asrc0 + (size_t)(ar+128)*128 + lc8,   smem + 4096 + w*512);
    gll16(Bsrc0 + (size_t)ar*128 + lc8,         smem + 16384 + w*512);
  }
  for (int s = 0; s < 12; ++s){
    __syncthreads();
    const int curA = (s & 1)*8192;
    const int curB = 16384 + (s & 1)*4096;
    if (s < 11){
      const int s1 = s + 1;
      const int g = s1 >> 2, kk = (s1 & 3)*32;
      const u16* Ap = (g == 0) ? Asrc0 : (g == 1) ? Asrc1 : Asrc2;
      const u16* Bp = (g == 0) ? Bsrc0 : (g == 1) ? Bsrc1 : cwb;
      const int nbA = (s1 & 1)*8192;
      const int nbB = 16384 + (s1 & 1)*4096;
      const int ar = w*16 + lr;
      gll16(Ap + (size_t)ar*128 + kk + lc8,       smem + nbA + w*512);
      gll16(Ap + (size_t)(ar+128)*128 + kk + lc8, smem + nbA + 4096 + w*512);
      gll16(Bp + (size_t)ar*128 + kk + lc8,       smem + nbB + w*512);
    }
    const bf16x8 af0 = *(const bf16x8*)&smem[curA + (w*32      + lm)*32 + q*8];
    const bf16x8 af1 = *(const bf16x8*)&smem[curA + (w*32 + 16 + lm)*32 + q*8];
    #pragma unroll
    for (int nt = 0; nt < 8; ++nt){
      const bf16x8 bf = *(const bf16x8*)&smem[curB + (nt*16 + lm)*32 + q*8];
      acc[0][nt] = __builtin_amdgcn_mfma_f32_16x16x32_bf16(af0, bf, acc[0][nt], 0, 0, 0);
      acc[1][nt] = __builtin_amdgcn_mfma_f32_16x16x32_bf16(af1, bf, acc[1][nt], 0, 0, 0);
    }
  }
  // epilogue in two 128-x passes; smem reused as [x][o] stride BPX
  #pragma unroll
  for (int pass = 0; pass < 2; ++pass){
    __syncthreads();
    if ((w >> 2) == pass){
      float xpart[8];
      #pragma unroll
      for (int nt = 0; nt < 8; ++nt) xpart[nt] = 0.f;
      const int wl = w & 3;
      #pragma unroll
      for (int mt = 0; mt < 2; ++mt){
        const int xg = w*32 + mt*16 + q*4;
        const int xl = wl*32 + mt*16 + q*4;
        #pragma unroll
        for (int nt = 0; nt < 8; ++nt){
          const int o = nt*16 + lm;
          const float f0v = sf0[o], cbv = scb[o];
          float v0 = acc[mt][nt][0] + f0v*sm[xg+0] + cbv;
          float v1 = acc[mt][nt][1] + f0v*sm[xg+1] + cbv;
          float v2 = acc[mt][nt][2] + f0v*sm[xg+2] + cbv;
          float v3 = acc[mt][nt][3] + f0v*sm[xg+3] + cbv;
          if (act){ v0 = gelu_f(v0); v1 = gelu_f(v1); v2 = gelu_f(v2); v3 = gelu_f(v3); }
          smem[(xl+0)*BPX + o] = f2bf(v0);
          smem[(xl+1)*BPX + o] = f2bf(v1);
          smem[(xl+2)*BPX + o] = f2bf(v2);
          smem[(xl+3)*BPX + o] = f2bf(v3);
          if (act){
            uint2 st;
            st.x = pk2(v0, v1);
            st.y = pk2(v2, v3);
            *(uint2*)&hI[((size_t)b*CC + o)*NN + x0 + xg] = st;
            xpart[nt] += v0*ssm2[xg+0] + v1*ssm2[xg+1] + v2*ssm2[xg+2] + v3*ssm2[xg+3];
          }
        }
      }
      if (act){
        #pragma unroll
        for (int nt = 0; nt < 8; ++nt){
          float v = xpart[nt];
          v += __shfl_xor(v, 16);
          v += __shfl_xor(v, 32);
          if (q == 0) atomicAdd(&x0next[b*CC + nt*16 + lm], v);
        }
      }
    }
    __syncthreads();
    {
      const int xr = t >> 2;
      const int oq = (t & 3)*32;
      const size_t dst = ((size_t)b*NN + x0 + pass*128 + xr)*CC + oq;
      #pragma unroll
      for (int j = 0; j < 4; ++j){
        const uint4 v = *(const uint4*)&smem[xr*BPX + oq + j*8];
        *(uint4*)&hT[dst + j*8] = v;
      }
    }
  }
}

// ---------------------------------------------------------------- final MLP (MFMA)
__global__ __launch_bounds__(256) void final_kernel(
    const u16* __restrict__ hT, const u16* __restrict__ w1T,
    const float* __restrict__ b1, const float* __restrict__ w2, const float* __restrict__ b2,
    float* __restrict__ out)
{
  __shared__ u16 sa[128*APX];
  __shared__ u16 sbt[128*APX];
  __shared__ float sb1[128], sw2[128];
  const int b  = blockIdx.x;
  const int x0 = blockIdx.y*128;
  const int t = threadIdx.x;
  const int w = t >> 6, l = t & 63, lm = l & 15, q = l >> 4;
  if (t < 128){ sb1[t] = b1[t]; sw2[t] = w2[t]; }
  const float b2v = b2[0];
  const f32x4 z4 = {0.f,0.f,0.f,0.f};
  f32x4 acc[2][8];
  #pragma unroll
  for (int mt = 0; mt < 2; ++mt)
    #pragma unroll
    for (int nt = 0; nt < 8; ++nt) acc[mt][nt] = z4;
  const u16* Ap = hT + ((size_t)b*NN + x0)*CC;
  const int row = t >> 2, ch = (t & 3)*8;
  for (int s = 0; s < 4; ++s){
    const int kk = s*32;
    __syncthreads();
    #pragma unroll
    for (int h = 0; h < 2; ++h){
      const int r = row + h*64;
      *(uint4*)&sa [r*APX + ch] = *(const uint4*)&Ap [(size_t)r*CC + kk + ch];
      *(uint4*)&sbt[r*APX + ch] = *(const uint4*)&w1T[(size_t)r*CC + kk + ch];
    }
    __syncthreads();
    bf16x8 af[2];
    af[0] = *(const bf16x8*)&sa[(w*32      + lm)*APX + q*8];
    af[1] = *(const bf16x8*)&sa[(w*32 + 16 + lm)*APX + q*8];
    #pragma unroll
    for (int nt = 0; nt < 8; ++nt){
      const bf16x8 bf = *(const bf16x8*)&sbt[(nt*16 + lm)*APX + q*8];
      acc[0][nt] = __builtin_amdgcn_mfma_f32_16x16x32_bf16(af[0], bf, acc[0][nt], 0, 0, 0);
      acc[1][nt] = __builtin_amdgcn_mfma_f32_16x16x32_bf16(af[1], bf, acc[1][nt], 0, 0, 0);
    }
  }
  #pragma unroll
  for (int mt = 0; mt < 2; ++mt){
    #pragma unroll
    for (int r = 0; r < 4; ++r){
      float s = 0.f;
      #pragma unroll
      for (int nt = 0; nt < 8; ++nt){
        const int f = nt*16 + lm;
        s += gelu_f(acc[mt][nt][r] + sb1[f]) * sw2[f];
      }
      s += __shfl_xor(s, 1);
      s += __shfl_xor(s, 2);
      s += __shfl_xor(s, 4);
      s += __shfl_xor(s, 8);
      if (lm == 0){
        const int x = x0 + w*32 + mt*16 + q*4 + r;
        out[(size_t)b*NN + x] = s + b2v;
      }
    }
  }
}

// ---------------------------------------------------------------- host
extern "C" void kernel_launch(void* const* d_in, const int* in_sizes, int n_in,
                              void* d_out, int out_size, void* d_ws, size_t ws_size,
                              hipStream_t stream)
{
  const float* X     = (const float*)d_in[0];
  const float* modes = (const float*)d_in[1];
  const float* fc0w  = (const float*)d_in[2];
  const float* fc0b  = (const float*)d_in[3];
  const float* wc    = (const float*)d_in[4];
  const float* wsm   = (const float*)d_in[5];
  const float* w0    = (const float*)d_in[6];
  const float* convw = (const float*)d_in[7];
  const float* convb = (const float*)d_in[8];
  const float* fc1w  = (const float*)d_in[9];
  const float* fc1b  = (const float*)d_in[10];
  const float* fc2w  = (const float*)d_in[11];
  const float* fc2b  = (const float*)d_in[12];
  float* out = (float*)d_out;

  const size_t nBKN = (size_t)BB*KK*NN;
  const size_t nBCK = (size_t)BB*CC*KK;
  const size_t nBC  = (size_t)BB*CC;
  const size_t nBN  = (size_t)BB*NN;

  // Path A: bf16 partials (2 x 16 x nBCK x 2B)
  const size_t need_A = 6*nBKN*2 + 2*(size_t)16*nBCK*2 + 2*nBCK*4 + 4*nBC*4
                      + 2*nBCK*2 + nBC*4 + 2*nBN*4 + (size_t)LL*CC*CC*2 + (size_t)CC*CC*2;
  const bool pathA = (ws_size >= need_A);

  char* p = (char*)d_ws;
  u16* bcs = (u16*)p; p += nBKN*2;
  u16* bss = (u16*)p; p += nBKN*2;
  u16* bcT = (u16*)p; p += nBKN*2;
  u16* bsT = (u16*)p; p += nBKN*2;
  u16* hI  = (u16*)p; p += nBKN*2;
  u16* hT  = (u16*)p; p += nBKN*2;
  u16* xcP = nullptr; u16* xsP = nullptr;
  if (pathA){
    xcP = (u16*)p; p += (size_t)16*nBCK*2;
    xsP = (u16*)p; p += (size_t)16*nBCK*2;
  }
  float* xcA = (float*)p; p += nBCK*4;
  float* xsA = (float*)p; p += nBCK*4;
  float* x0A = (float*)p; p += 4*nBC*4;    // 4 per-layer slots
  u16* fcb = (u16*)p; p += nBCK*2;
  u16* fsb = (u16*)p; p += nBCK*2;
  float* f0b = (float*)p; p += nBC*4;
  float* mA  = (float*)p; p += nBN*4;
  float* sm2 = (float*)p; p += nBN*4;
  u16* cwb = (u16*)p; p += (size_t)LL*CC*CC*2;
  u16* w1T = (u16*)p; p += (size_t)CC*CC*2;

  hipMemsetAsync(x0A, 0, 4*nBC*sizeof(float), stream);
  cvt_kernel<<<dim3(80), 256, 0, stream>>>(convw, fc1w, cwb, w1T);
  bases_kernel<<<dim3(BB, NN/64), 256, 0, stream>>>(X, modes, bcs, bss, bcT, bsT, mA, sm2);
  fc0_kernel<<<dim3(BB, NN/128), 256, 0, stream>>>(X, fc0w, fc0b, sm2, hT, hI, x0A);

  for (int l = 0; l < LL; ++l){
    if (pathA){
      proj512_kernel<<<dim3(BB, 16, 2), 512, 0, stream>>>(hI, bcs, bss, xcP, xsP);
      reduce_f0_kernel<<<dim3(1024 + BB), 128, 0, stream>>>(xcP, xsP, xcA, xsA,
          x0A + (size_t)l*nBC, w0 + (size_t)l*CC*CC, f0b);
    } else {
      hipMemsetAsync(xcA, 0, 2*nBCK*sizeof(float), stream);
      proj_atomic_kernel<<<dim3(BB, 16), 256, 0, stream>>>(hI, bcs, bss, xcA, xsA);
      f0_kernel<<<dim3(BB), 128, 0, stream>>>(x0A + (size_t)l*nBC, w0 + (size_t)l*CC*CC, f0b);
    }
    mix_kernel<<<dim3(128, 4), 256, 0, stream>>>(xcA, xsA,
        wc + (size_t)l*CC*CC*KK, wsm + (size_t)l*CC*CC*KK, fcb, fsb);
    fused_kernel<<<dim3(BB, NN/256), 512, 0, stream>>>(
        bcT, bsT, hT, fcb, fsb,
        cwb + (size_t)l*CC*CC, convb + (size_t)l*CC,
        f0b, mA, sm2, hI,
        x0A + (size_t)(l+1 < LL ? l+1 : 0)*nBC,
        (l < LL-1) ? 1 : 0);
  }
  final_kernel<<<dim3(BB, NN/128), 256, 0, stream>>>(hT, w1T, fc1b, fc2w, fc2b, out);
}